// Round 1
// baseline (156.857 us; speedup 1.0000x reference)
//
#include <hip/hip_runtime.h>

// Problem constants: B=128, N=64, D=64
// Outputs (flat, in order): kappa [B,N,N]=524288, diff [B,N,N,D]=33554432,
//                           gamma [B]=128, kappa_grad [B,N,N,D]=33554432

#define NB 128
#define NP 64
#define ND 64

// ---------------- Kernel 1: per-batch dist^2 + exact lower median -> gamma --
__global__ __launch_bounds__(256) void rbf_median_kernel(
    const float* __restrict__ in1, const float* __restrict__ in2,
    float* __restrict__ out_gamma, float* __restrict__ gws)
{
    __shared__ float sA[64 * 65];   // padded stride 65 -> 2-way bank alias (free)
    __shared__ float sB[64 * 65];
    __shared__ float sD[4096];

    const int b = blockIdx.x;
    const int t = threadIdx.x;
    const float* A  = in1 + b * 4096;
    const float* Bv = in2 + b * 4096;

    for (int e = t; e < 4096; e += 256) {
        int r = e >> 6, c = e & 63;
        sA[r * 65 + c] = A[e];
        sB[r * 65 + c] = Bv[e];
    }
    __syncthreads();

    // dist_sq[i][j] = sum_d (A[i,d]-B[j,d])^2
    for (int s = 0; s < 16; ++s) {
        int idx = t + s * 256;
        int i = idx >> 6, j = idx & 63;
        const float* ra = &sA[i * 65];   // i uniform per wave -> broadcast
        const float* rb = &sB[j * 65];   // j = lane -> banks (j+d)%32, 2-way
        float acc = 0.f;
        #pragma unroll
        for (int d = 0; d < 64; ++d) {
            float df = ra[d] - rb[d];
            acc = fmaf(df, df, acc);
        }
        sD[idx] = acc;
    }
    __syncthreads();

    // bitonic sort of 4096 values; exact, tie-safe
    for (int k = 2; k <= 4096; k <<= 1) {
        for (int j = k >> 1; j > 0; j >>= 1) {
            for (int s = 0; s < 16; ++s) {
                int i = t + s * 256;
                int ixj = i ^ j;
                if (ixj > i) {                 // pairs disjoint within a stage
                    float x = sD[i], y = sD[ixj];
                    bool up = ((i & k) == 0);
                    if ((x > y) == up) { sD[i] = y; sD[ixj] = x; }
                }
            }
            __syncthreads();
        }
    }

    if (t == 0) {
        float med   = sD[2047];                       // lower median: sorted[(n-1)/2]
        float h     = med / (2.0f * logf((float)NP + 1.0f));
        float sigma = sqrtf(h);
        float gamma = 1.0f / (1e-8f + 2.0f * sigma * sigma);
        out_gamma[b] = gamma;
        gws[b]       = gamma;
    }
}

// ---------------- Kernel 2: diff / kappa / kappa_grad (write-bound) ---------
__global__ __launch_bounds__(256) void rbf_out_kernel(
    const float* __restrict__ in1, const float* __restrict__ in2,
    const float* __restrict__ gws,
    float* __restrict__ out_kappa, float* __restrict__ out_diff,
    float* __restrict__ out_kgrad)
{
    const int bi   = blockIdx.x;      // b*64 + i
    const int b    = bi >> 6;
    const int t    = threadIdx.x;
    const int wave = t >> 6;          // 0..3
    const int lane = t & 63;
    const int jo   = lane >> 4;       // 0..3 : j-subgroup within wave
    const int q    = lane & 15;       // 0..15: position within j-group
    const int d4   = q << 2;          // 4 d's per lane via float4

    const float  gamma = gws[b];
    const float4 a4 = *reinterpret_cast<const float4*>(in1 + ((size_t)bi << 6) + d4);

    const float* in2b     = in2      + ((size_t)b  << 12);
    float*       diffBase = out_diff + ((size_t)bi << 12);
    float*       kgBase   = out_kgrad+ ((size_t)bi << 12);
    float*       kapBase  = out_kappa+ ((size_t)bi << 6);

    #pragma unroll
    for (int it = 0; it < 4; ++it) {
        int j = wave * 16 + it * 4 + jo;   // each wave covers 16 distinct j
        float4 b4 = *reinterpret_cast<const float4*>(in2b + (j << 6) + d4);
        float4 df;
        df.x = a4.x - b4.x; df.y = a4.y - b4.y;
        df.z = a4.z - b4.z; df.w = a4.w - b4.w;
        *reinterpret_cast<float4*>(diffBase + (j << 6) + d4) = df;

        float ss = df.x*df.x + df.y*df.y + df.z*df.z + df.w*df.w;
        #pragma unroll
        for (int off = 1; off < 16; off <<= 1)   // reduce within 16-lane group
            ss += __shfl_xor(ss, off, 64);

        float kap = expf(-gamma * ss);
        if (q == 0) kapBase[j] = kap;

        float m = -2.0f * gamma * kap;
        float4 kg;
        kg.x = m * df.x; kg.y = m * df.y; kg.z = m * df.z; kg.w = m * df.w;
        *reinterpret_cast<float4*>(kgBase + (j << 6) + d4) = kg;
    }
}

extern "C" void kernel_launch(void* const* d_in, const int* in_sizes, int n_in,
                              void* d_out, int out_size, void* d_ws, size_t ws_size,
                              hipStream_t stream) {
    const float* in1 = (const float*)d_in[0];
    const float* in2 = (const float*)d_in[1];
    float* out = (float*)d_out;

    float* out_kappa = out;                              // 524288
    float* out_diff  = out + 524288;                     // 33554432
    float* out_gamma = out + 524288 + 33554432;          // 128
    float* out_kgrad = out_gamma + 128;                  // 33554432
    float* gws       = (float*)d_ws;                     // 128 floats scratch

    rbf_median_kernel<<<NB, 256, 0, stream>>>(in1, in2, out_gamma, gws);
    rbf_out_kernel<<<NB * NP, 256, 0, stream>>>(in1, in2, gws,
                                                out_kappa, out_diff, out_kgrad);
}

// Round 2
// 68.901 us; speedup vs baseline: 2.2766x; 2.2766x over previous
//
#include <hip/hip_runtime.h>

// Problem constants: B=128, N=64, D=64
// Outputs (flat, in order): kappa [B,N,N]=524288, diff [B,N,N,D]=33554432,
//                           gamma [B]=128, kappa_grad [B,N,N,D]=33554432

#define NB 128
#define NP 64
#define ND 64

// ---------------- Kernel 1: per-batch dist^2 + exact lower median -> gamma --
// 256 threads/block, one block per batch.
// Phase 1: stage A,B in LDS (stride 65). Phase 2: each thread computes a 4x4
// (i,j) tile of dist^2 into registers (8 LDS reads per d, <=2-way conflicts).
// Phase 3: radix-select bisection on float bit patterns for the exact
// 2047-th smallest (lower median) -- 32 rounds, registers + shfl + 1 LDS
// scalar per wave per round. No sort, no big LDS traffic.
__global__ __launch_bounds__(256) void rbf_median_kernel(
    const float* __restrict__ in1, const float* __restrict__ in2,
    float* __restrict__ out_gamma, float* __restrict__ gws)
{
    __shared__ float sA[64 * 65];
    __shared__ float sB[64 * 65];
    __shared__ int   sCnt[4];

    const int b = blockIdx.x;
    const int t = threadIdx.x;
    const int wave = t >> 6;
    const int lane = t & 63;
    const float* A  = in1 + b * 4096;
    const float* Bv = in2 + b * 4096;

    for (int e = t; e < 4096; e += 256) {
        int r = e >> 6, c = e & 63;
        sA[r * 65 + c] = A[e];
        sB[r * 65 + c] = Bv[e];
    }
    __syncthreads();

    // 4x4 register tile per thread: i0 = 4*(t>>4), j0 = 4*(t&15)
    const int i0 = (t >> 4) << 2;
    const int j0 = (t & 15) << 2;
    float acc[4][4];
    #pragma unroll
    for (int r = 0; r < 4; ++r)
        #pragma unroll
        for (int c = 0; c < 4; ++c) acc[r][c] = 0.f;

    const float* pa = &sA[i0 * 65];
    const float* pb = &sB[j0 * 65];
    #pragma unroll 4
    for (int d = 0; d < 64; ++d) {
        float ar[4], bc[4];
        #pragma unroll
        for (int r = 0; r < 4; ++r) ar[r] = pa[r * 65 + d];
        #pragma unroll
        for (int c = 0; c < 4; ++c) bc[c] = pb[c * 65 + d];
        #pragma unroll
        for (int r = 0; r < 4; ++r)
            #pragma unroll
            for (int c = 0; c < 4; ++c) {
                float df = ar[r] - bc[c];
                acc[r][c] = fmaf(df, df, acc[r][c]);
            }
    }

    // bit patterns (all values >= 0 -> unsigned order == float order)
    unsigned uv[16];
    #pragma unroll
    for (int r = 0; r < 4; ++r)
        #pragma unroll
        for (int c = 0; c < 4; ++c) uv[r * 4 + c] = __float_as_uint(acc[r][c]);

    // radix-select the k-th smallest, k = (4096-1)/2 = 2047 (zero-based)
    unsigned pref = 0;
    int need = 2047;
    for (int bit = 31; bit >= 0; --bit) {
        unsigned pshift = pref >> bit;   // pref's 'bit' is still 0 here
        int cnt = 0;
        #pragma unroll
        for (int x = 0; x < 16; ++x) cnt += ((uv[x] >> bit) == pshift) ? 1 : 0;
        #pragma unroll
        for (int off = 1; off < 64; off <<= 1) cnt += __shfl_xor(cnt, off, 64);
        if (lane == 0) sCnt[wave] = cnt;
        __syncthreads();
        int c0 = sCnt[0] + sCnt[1] + sCnt[2] + sCnt[3];
        if (need >= c0) { pref |= (1u << bit); need -= c0; }  // uniform update
        __syncthreads();
    }

    if (t == 0) {
        float med   = __uint_as_float(pref);          // exact sorted[2047]
        float h     = med / (2.0f * logf((float)NP + 1.0f));
        float sigma = sqrtf(h);
        float gamma = 1.0f / (1e-8f + 2.0f * sigma * sigma);
        out_gamma[b] = gamma;
        gws[b]       = gamma;
    }
}

// ---------------- Kernel 2: diff / kappa / kappa_grad (write-bound) ---------
__global__ __launch_bounds__(256) void rbf_out_kernel(
    const float* __restrict__ in1, const float* __restrict__ in2,
    const float* __restrict__ gws,
    float* __restrict__ out_kappa, float* __restrict__ out_diff,
    float* __restrict__ out_kgrad)
{
    const int bi   = blockIdx.x;      // b*64 + i
    const int b    = bi >> 6;
    const int t    = threadIdx.x;
    const int wave = t >> 6;          // 0..3
    const int lane = t & 63;
    const int jo   = lane >> 4;       // 0..3 : j-subgroup within wave
    const int q    = lane & 15;       // 0..15: position within j-group
    const int d4   = q << 2;          // 4 d's per lane via float4

    const float  gamma = gws[b];
    const float4 a4 = *reinterpret_cast<const float4*>(in1 + ((size_t)bi << 6) + d4);

    const float* in2b     = in2      + ((size_t)b  << 12);
    float*       diffBase = out_diff + ((size_t)bi << 12);
    float*       kgBase   = out_kgrad+ ((size_t)bi << 12);
    float*       kapBase  = out_kappa+ ((size_t)bi << 6);

    #pragma unroll
    for (int it = 0; it < 4; ++it) {
        int j = wave * 16 + it * 4 + jo;   // each wave covers 16 distinct j
        float4 b4 = *reinterpret_cast<const float4*>(in2b + (j << 6) + d4);
        float4 df;
        df.x = a4.x - b4.x; df.y = a4.y - b4.y;
        df.z = a4.z - b4.z; df.w = a4.w - b4.w;
        *reinterpret_cast<float4*>(diffBase + (j << 6) + d4) = df;

        float ss = df.x*df.x + df.y*df.y + df.z*df.z + df.w*df.w;
        #pragma unroll
        for (int off = 1; off < 16; off <<= 1)   // reduce within 16-lane group
            ss += __shfl_xor(ss, off, 64);

        float kap = __expf(-gamma * ss);
        if (q == 0) kapBase[j] = kap;

        float m = -2.0f * gamma * kap;
        float4 kg;
        kg.x = m * df.x; kg.y = m * df.y; kg.z = m * df.z; kg.w = m * df.w;
        *reinterpret_cast<float4*>(kgBase + (j << 6) + d4) = kg;
    }
}

extern "C" void kernel_launch(void* const* d_in, const int* in_sizes, int n_in,
                              void* d_out, int out_size, void* d_ws, size_t ws_size,
                              hipStream_t stream) {
    const float* in1 = (const float*)d_in[0];
    const float* in2 = (const float*)d_in[1];
    float* out = (float*)d_out;

    float* out_kappa = out;                              // 524288
    float* out_diff  = out + 524288;                     // 33554432
    float* out_gamma = out + 524288 + 33554432;          // 128
    float* out_kgrad = out_gamma + 128;                  // 33554432
    float* gws       = (float*)d_ws;                     // 128 floats scratch

    rbf_median_kernel<<<NB, 256, 0, stream>>>(in1, in2, out_gamma, gws);
    rbf_out_kernel<<<NB * NP, 256, 0, stream>>>(in1, in2, gws,
                                                out_kappa, out_diff, out_kgrad);
}

// Round 3
// 63.133 us; speedup vs baseline: 2.4845x; 1.0914x over previous
//
#include <hip/hip_runtime.h>

// Problem constants: B=128, N=64, D=64
// Outputs (flat, in order): kappa [B,N,N]=524288, diff [B,N,N,D]=33554432,
//                           gamma [B,1,1,1]=128, kappa_grad [B,N,N,D]=33554432
//
// Structure:
//   A: write diff (128MB) + dist^2 into the kappa slot (2MB scratch, same shape)
//   B: exact lower-median select per batch from stored dist^2 -> gamma slot
//   C: overwrite kappa with exp(-g*d2), write kappa_grad (130MB)

#define NB 128
#define NP 64

// ---------------- Kernel A: diff + dist^2 (write-bound, full GPU) -----------
__global__ __launch_bounds__(256) void rbf_diff_kernel(
    const float* __restrict__ in1, const float* __restrict__ in2,
    float* __restrict__ out_diff, float* __restrict__ dist2 /* = kappa slot */)
{
    const int bi   = blockIdx.x;      // b*64 + i
    const int b    = bi >> 6;
    const int t    = threadIdx.x;
    const int wave = t >> 6;          // 0..3
    const int lane = t & 63;
    const int jo   = lane >> 4;       // 0..3
    const int q    = lane & 15;       // 0..15
    const int d4   = q << 2;

    const float4 a4 = *reinterpret_cast<const float4*>(in1 + ((size_t)bi << 6) + d4);
    const float* in2b     = in2      + ((size_t)b  << 12);
    float*       diffBase = out_diff + ((size_t)bi << 12);
    float*       d2Base   = dist2    + ((size_t)bi << 6);

    #pragma unroll
    for (int it = 0; it < 4; ++it) {
        int j = wave * 16 + it * 4 + jo;
        float4 b4 = *reinterpret_cast<const float4*>(in2b + (j << 6) + d4);
        float4 df;
        df.x = a4.x - b4.x; df.y = a4.y - b4.y;
        df.z = a4.z - b4.z; df.w = a4.w - b4.w;
        *reinterpret_cast<float4*>(diffBase + (j << 6) + d4) = df;

        float ss = df.x*df.x + df.y*df.y + df.z*df.z + df.w*df.w;
        #pragma unroll
        for (int off = 1; off < 16; off <<= 1)
            ss += __shfl_xor(ss, off, 64);
        if (q == 0) d2Base[j] = ss;
    }
}

// ---------------- Kernel B: exact rank-2047 select via 3-level histogram ----
__global__ __launch_bounds__(256) void rbf_select_kernel(
    const float* __restrict__ dist2, float* __restrict__ out_gamma)
{
    __shared__ int hist[4096];        // 16 KB
    __shared__ int sWave[4];
    __shared__ int sSel[2];

    const int b    = blockIdx.x;
    const int t    = threadIdx.x;
    const int wave = t >> 6;
    const int lane = t & 63;

    const float4* p = reinterpret_cast<const float4*>(dist2 + b * 4096);
    unsigned uv[16];
    #pragma unroll
    for (int s = 0; s < 4; ++s) {
        float4 v = p[t + 256 * s];
        uv[s*4+0] = __float_as_uint(v.x);
        uv[s*4+1] = __float_as_uint(v.y);
        uv[s*4+2] = __float_as_uint(v.z);
        uv[s*4+3] = __float_as_uint(v.w);
    }
    bool act[16];
    #pragma unroll
    for (int x = 0; x < 16; ++x) act[x] = true;

    int need = 2047;                  // zero-based lower median of 4096
    unsigned result = 0;

    const int shifts[3] = {19, 7, 0}; // bits 30:19, 18:7, 6:0 (bit31==0: d2>=0)
    const int nbits [3] = {12, 12, 7};
    for (int lv = 0; lv < 3; ++lv) {
        const int      sh   = shifts[lv];
        const unsigned mask = (1u << nbits[lv]) - 1u;
        const int      NB_  = 1 << nbits[lv];

        for (int x = t; x < NB_; x += 256) hist[x] = 0;
        __syncthreads();
        #pragma unroll
        for (int x = 0; x < 16; ++x)
            if (act[x]) atomicAdd(&hist[(uv[x] >> sh) & mask], 1);
        __syncthreads();

        int lbins[16]; int lsum = 0;
        #pragma unroll
        for (int x = 0; x < 16; ++x) {
            int idx = t * 16 + x;
            int h = (idx < NB_) ? hist[idx] : 0;
            lbins[x] = h; lsum += h;
        }
        int v = lsum;                                   // inclusive wave scan
        #pragma unroll
        for (int off = 1; off < 64; off <<= 1) {
            int o = __shfl_up(v, off, 64);
            if (lane >= off) v += o;
        }
        if (lane == 63) sWave[wave] = v;
        __syncthreads();
        int woff = 0;
        for (int w = 0; w < wave; ++w) woff += sWave[w];
        int excl = woff + v - lsum;                     // exclusive prefix
        if (lsum > 0 && need >= excl && need < excl + lsum) {
            int acc = excl;                             // exactly one thread
            #pragma unroll
            for (int x = 0; x < 16; ++x) {
                if (need < acc + lbins[x]) { sSel[0] = t*16 + x; sSel[1] = need - acc; break; }
                acc += lbins[x];
            }
        }
        __syncthreads();
        int bin = sSel[0]; need = sSel[1];
        result |= ((unsigned)bin) << sh;
        #pragma unroll
        for (int x = 0; x < 16; ++x)
            act[x] = act[x] && (((uv[x] >> sh) & mask) == (unsigned)bin);
        __syncthreads();                                // hist reused next level
    }

    if (t == 0) {
        float med   = __uint_as_float(result);          // exact sorted[2047]
        float h     = med / (2.0f * logf((float)NP + 1.0f));
        float sigma = sqrtf(h);
        float gamma = 1.0f / (1e-8f + 2.0f * sigma * sigma);
        out_gamma[b] = gamma;
    }
}

// ---------------- Kernel C: kappa + kappa_grad (write-bound) ----------------
__global__ __launch_bounds__(256) void rbf_out_kernel(
    const float* __restrict__ in1, const float* __restrict__ in2,
    const float* __restrict__ gsrc,
    float* __restrict__ out_kappa, float* __restrict__ out_kgrad)
{
    const int bi   = blockIdx.x;
    const int b    = bi >> 6;
    const int t    = threadIdx.x;
    const int wave = t >> 6;
    const int lane = t & 63;
    const int jo   = lane >> 4;
    const int q    = lane & 15;
    const int d4   = q << 2;

    const float  gamma = gsrc[b];
    const float4 a4 = *reinterpret_cast<const float4*>(in1 + ((size_t)bi << 6) + d4);

    const float* in2b    = in2       + ((size_t)b  << 12);
    float*       kgBase  = out_kgrad + ((size_t)bi << 12);
    float*       kapBase = out_kappa + ((size_t)bi << 6);

    #pragma unroll
    for (int it = 0; it < 4; ++it) {
        int j = wave * 16 + it * 4 + jo;
        float4 b4 = *reinterpret_cast<const float4*>(in2b + (j << 6) + d4);
        float4 df;
        df.x = a4.x - b4.x; df.y = a4.y - b4.y;
        df.z = a4.z - b4.z; df.w = a4.w - b4.w;

        float ss = df.x*df.x + df.y*df.y + df.z*df.z + df.w*df.w;
        #pragma unroll
        for (int off = 1; off < 16; off <<= 1)
            ss += __shfl_xor(ss, off, 64);

        float kap = __expf(-gamma * ss);
        if (q == 0) kapBase[j] = kap;

        float m = -2.0f * gamma * kap;
        float4 kg;
        kg.x = m * df.x; kg.y = m * df.y; kg.z = m * df.z; kg.w = m * df.w;
        *reinterpret_cast<float4*>(kgBase + (j << 6) + d4) = kg;
    }
}

extern "C" void kernel_launch(void* const* d_in, const int* in_sizes, int n_in,
                              void* d_out, int out_size, void* d_ws, size_t ws_size,
                              hipStream_t stream) {
    const float* in1 = (const float*)d_in[0];
    const float* in2 = (const float*)d_in[1];
    float* out = (float*)d_out;

    float* out_kappa = out;                              // 524288 (scratch for dist^2 in A)
    float* out_diff  = out + 524288;                     // 33554432
    float* out_gamma = out + 524288 + 33554432;          // 128
    float* out_kgrad = out_gamma + 128;                  // 33554432

    rbf_diff_kernel  <<<NB * NP, 256, 0, stream>>>(in1, in2, out_diff, out_kappa);
    rbf_select_kernel<<<NB,      256, 0, stream>>>(out_kappa, out_gamma);
    rbf_out_kernel   <<<NB * NP, 256, 0, stream>>>(in1, in2, out_gamma,
                                                   out_kappa, out_kgrad);
}

// Round 6
// 62.834 us; speedup vs baseline: 2.4964x; 1.0048x over previous
//
#include <hip/hip_runtime.h>

// Problem constants: B=128, N=64, D=64
// Outputs (flat): kappa [B,N,N]=524288, diff [B,N,N,D]=33554432,
//                 gamma [B,1,1,1]=128, kappa_grad [B,N,N,D]=33554432
//
// Two plain dispatches (cooperative launch fails under graph capture):
//  k1 (1024 blocks): blocks 0..127  -> exact per-batch lower-median -> gamma
//                    blocks 128..1023 -> write diff rows [0, 2688)
//  k2 (8192 blocks): kappa + kappa_grad for all rows; diff rows [2688, 8192)

#define NBATCH   128
#define K1_GRID  1024
#define K1_WROWS 3
#define K1_ROWS  2688   // (1024-128)*3

typedef float f32x4 __attribute__((ext_vector_type(4)));

__device__ __forceinline__ void nt_store4(float* p, float x, float y, float z, float w) {
    f32x4 v = {x, y, z, w};
    __builtin_nontemporal_store(v, reinterpret_cast<f32x4*>(p));
}

__global__ __launch_bounds__(256) void rbf_k1(
    const float* __restrict__ in1, const float* __restrict__ in2,
    float* __restrict__ out_diff, float* __restrict__ out_gamma)
{
    // 32 KB shared: A^T,B^T during dist^2; reused as histogram afterwards
    __shared__ float smem[2 * 64 * 64];
    __shared__ int   sWave[4];
    __shared__ int   sSel[2];

    const int p    = blockIdx.x;
    const int t    = threadIdx.x;
    const int wave = t >> 6;
    const int lane = t & 63;

    if (p >= NBATCH) {
        // ---- diff writer: rows 3*(p-128) .. +2 ----
        const int jo = lane >> 4;
        const int q  = lane & 15;
        const int d4 = q << 2;
        const int w  = p - NBATCH;
        for (int r = 0; r < K1_WROWS; ++r) {
            const int bi = w * K1_WROWS + r;
            const int b  = bi >> 6;
            const float4 a4 = *reinterpret_cast<const float4*>(in1 + ((size_t)bi << 6) + d4);
            const float* in2b = in2 + ((size_t)b << 12);
            float* diffBase = out_diff + ((size_t)bi << 12);
            #pragma unroll
            for (int it = 0; it < 4; ++it) {
                int j = wave * 16 + it * 4 + jo;
                float4 b4 = *reinterpret_cast<const float4*>(in2b + (j << 6) + d4);
                nt_store4(diffBase + (j << 6) + d4,
                          a4.x - b4.x, a4.y - b4.y, a4.z - b4.z, a4.w - b4.w);
            }
        }
        return;
    }

    // ---- median for batch p ----
    float* sAT = smem;            // [d][i], stride 64
    float* sBT = smem + 4096;     // [d][j], stride 64

    const float* A  = in1 + p * 4096;
    const float* Bv = in2 + p * 4096;

    // stage transposed: thread handles 4 float4s (i = e>>4, d0 = (e&15)*4)
    for (int e = t; e < 1024; e += 256) {
        int i = e >> 4, d0 = (e & 15) << 2;
        float4 av = *reinterpret_cast<const float4*>(A  + (i << 6) + d0);
        float4 bv = *reinterpret_cast<const float4*>(Bv + (i << 6) + d0);
        sAT[(d0+0)*64 + i] = av.x; sAT[(d0+1)*64 + i] = av.y;
        sAT[(d0+2)*64 + i] = av.z; sAT[(d0+3)*64 + i] = av.w;
        sBT[(d0+0)*64 + i] = bv.x; sBT[(d0+1)*64 + i] = bv.y;
        sBT[(d0+2)*64 + i] = bv.z; sBT[(d0+3)*64 + i] = bv.w;
    }
    __syncthreads();

    // 4x4 register tile: i0 = 4*(t>>4), j0 = 4*(t&15); 2 x ds_read_b128 per d
    const int i0 = (t >> 4) << 2;
    const int j0 = (t & 15) << 2;
    float acc[4][4];
    #pragma unroll
    for (int r = 0; r < 4; ++r)
        #pragma unroll
        for (int c = 0; c < 4; ++c) acc[r][c] = 0.f;

    #pragma unroll 8
    for (int d = 0; d < 64; ++d) {
        float4 av = *reinterpret_cast<const float4*>(&sAT[d * 64 + i0]);
        float4 bv = *reinterpret_cast<const float4*>(&sBT[d * 64 + j0]);
        float ar[4] = {av.x, av.y, av.z, av.w};
        float bc[4] = {bv.x, bv.y, bv.z, bv.w};
        #pragma unroll
        for (int r = 0; r < 4; ++r)
            #pragma unroll
            for (int c = 0; c < 4; ++c) {
                float df = ar[r] - bc[c];
                acc[r][c] = fmaf(df, df, acc[r][c]);
            }
    }

    unsigned uv[16];
    #pragma unroll
    for (int r = 0; r < 4; ++r)
        #pragma unroll
        for (int c = 0; c < 4; ++c) uv[r * 4 + c] = __float_as_uint(acc[r][c]);

    __syncthreads();                 // all LDS reads done; smem reused as hist
    int* hist = reinterpret_cast<int*>(smem);

    bool act[16];
    #pragma unroll
    for (int x = 0; x < 16; ++x) act[x] = true;

    int need = 2047;                 // zero-based lower median of 4096
    unsigned result = 0;

    const int shifts[3] = {19, 7, 0};   // bits 30:19, 18:7, 6:0 (bit31==0: d2>=0)
    const int nbits [3] = {12, 12, 7};
    for (int lv = 0; lv < 3; ++lv) {
        const int      sh   = shifts[lv];
        const unsigned mask = (1u << nbits[lv]) - 1u;
        const int      NB_  = 1 << nbits[lv];

        for (int x = t; x < NB_; x += 256) hist[x] = 0;
        __syncthreads();
        #pragma unroll
        for (int x = 0; x < 16; ++x)
            if (act[x]) atomicAdd(&hist[(uv[x] >> sh) & mask], 1);
        __syncthreads();

        int lbins[16]; int lsum = 0;
        #pragma unroll
        for (int x = 0; x < 16; ++x) {
            int idx = t * 16 + x;
            int h = (idx < NB_) ? hist[idx] : 0;
            lbins[x] = h; lsum += h;
        }
        int v = lsum;                                // inclusive wave scan
        #pragma unroll
        for (int off = 1; off < 64; off <<= 1) {
            int o = __shfl_up(v, off, 64);
            if (lane >= off) v += o;
        }
        if (lane == 63) sWave[wave] = v;
        __syncthreads();
        int woff = 0;
        for (int w2 = 0; w2 < wave; ++w2) woff += sWave[w2];
        int excl = woff + v - lsum;                  // exclusive prefix
        if (lsum > 0 && need >= excl && need < excl + lsum) {
            int acc2 = excl;                         // exactly one thread hits
            #pragma unroll
            for (int x = 0; x < 16; ++x) {
                if (need < acc2 + lbins[x]) { sSel[0] = t*16 + x; sSel[1] = need - acc2; break; }
                acc2 += lbins[x];
            }
        }
        __syncthreads();
        int bin = sSel[0]; need = sSel[1];
        result |= ((unsigned)bin) << sh;
        #pragma unroll
        for (int x = 0; x < 16; ++x)
            act[x] = act[x] && (((uv[x] >> sh) & mask) == (unsigned)bin);
        __syncthreads();
    }

    if (t == 0) {
        float med   = __uint_as_float(result);       // exact sorted[2047]
        float h     = med / (2.0f * logf(64.0f + 1.0f));
        float sigma = sqrtf(h);
        float gamma = 1.0f / (1e-8f + 2.0f * sigma * sigma);
        out_gamma[p] = gamma;
    }
}

__global__ __launch_bounds__(256) void rbf_k2(
    const float* __restrict__ in1, const float* __restrict__ in2,
    const float* __restrict__ gsrc,
    float* __restrict__ out_kappa, float* __restrict__ out_diff,
    float* __restrict__ out_kgrad)
{
    const int bi   = blockIdx.x;
    const int b    = bi >> 6;
    const int t    = threadIdx.x;
    const int wave = t >> 6;
    const int lane = t & 63;
    const int jo   = lane >> 4;
    const int q    = lane & 15;
    const int d4   = q << 2;

    const float  gamma = gsrc[b];
    const float4 a4 = *reinterpret_cast<const float4*>(in1 + ((size_t)bi << 6) + d4);

    const float* in2b    = in2       + ((size_t)b  << 12);
    float*       kgBase  = out_kgrad + ((size_t)bi << 12);
    float*       kapBase = out_kappa + ((size_t)bi << 6);
    float*       diffBase= out_diff  + ((size_t)bi << 12);
    const bool   doDiff  = (bi >= K1_ROWS);

    #pragma unroll
    for (int it = 0; it < 4; ++it) {
        int j = wave * 16 + it * 4 + jo;
        float4 b4 = *reinterpret_cast<const float4*>(in2b + (j << 6) + d4);
        float4 df;
        df.x = a4.x - b4.x; df.y = a4.y - b4.y;
        df.z = a4.z - b4.z; df.w = a4.w - b4.w;
        if (doDiff)
            nt_store4(diffBase + (j << 6) + d4, df.x, df.y, df.z, df.w);

        float ss = df.x*df.x + df.y*df.y + df.z*df.z + df.w*df.w;
        #pragma unroll
        for (int off = 1; off < 16; off <<= 1)
            ss += __shfl_xor(ss, off, 64);

        float kap = __expf(-gamma * ss);
        if (q == 0) kapBase[j] = kap;

        float m = -2.0f * gamma * kap;
        nt_store4(kgBase + (j << 6) + d4, m * df.x, m * df.y, m * df.z, m * df.w);
    }
}

extern "C" void kernel_launch(void* const* d_in, const int* in_sizes, int n_in,
                              void* d_out, int out_size, void* d_ws, size_t ws_size,
                              hipStream_t stream) {
    const float* in1 = (const float*)d_in[0];
    const float* in2 = (const float*)d_in[1];
    float* out = (float*)d_out;

    float* out_kappa = out;                              // 524288
    float* out_diff  = out + 524288;                     // 33554432
    float* out_gamma = out + 524288 + 33554432;          // 128
    float* out_kgrad = out_gamma + 128;                  // 33554432

    rbf_k1<<<K1_GRID,     256, 0, stream>>>(in1, in2, out_diff, out_gamma);
    rbf_k2<<<NBATCH * 64, 256, 0, stream>>>(in1, in2, out_gamma,
                                            out_kappa, out_diff, out_kgrad);
}